// Round 19
// baseline (212.432 us; speedup 1.0000x reference)
//
#include <hip/hip_runtime.h>

// Problem constants (fixed by setup_inputs):
//   a_arc, s_arc : [64, 1024, 1024] f32
//   adds, pos    : [64, 1024] int32 in [0, 50)
constexpr int NPOS  = 50;
constexpr int NBINS = NPOS * NPOS;   // 2500
constexpr int SL    = 1024;
constexpr int BZ    = 64;
constexpr float ALPHA = 0.3f;

using f32x4  = __attribute__((ext_vector_type(4))) float;
using bf16x8 = __attribute__((ext_vector_type(8))) short;

// ---------------- hist (MFMA, LDS-staged) config ----------------
constexpr int H_THREADS = 256;                  // 4 waves; wave w owns q-tile w
constexpr int ROWS_PB   = 16;                   // rows per block (one M-tile)
constexpr int H_BLOCKS  = BZ * (SL / ROWS_PB);  // 4096
constexpr int KSTEPS    = SL / 32;              // 32
constexpr int APAD      = 1032;                 // row stride in LDS (pad 8)

// ---------------- efrag config (layout: [b][ks][qt][lane] uint4) ----------
constexpr int E_THREADS = 256;
constexpr int E_BLOCKS  = (BZ * KSTEPS * 64) / E_THREADS;   // 512

// ---------------- apply config (R16 verbatim) ----------------
constexpr int A_THREADS      = 256;
constexpr int ROWS_PER_BLOCK = 32;
constexpr int BLOCKS_PER_B   = SL / ROWS_PER_BLOCK;   // 32
constexpr int A_BLOCKS       = BZ * BLOCKS_PER_B;     // 2048

// ---------------------------------------------------------------------------
// Kernel 0: prebuilt one-hot E fragments (R9-verified mapping), relaid as
// [b][ks][qt][lane] so each wave's per-K-step fragment read is 1KB coalesced.
// ---------------------------------------------------------------------------
__global__ __launch_bounds__(E_THREADS) void efrag_kernel(
    const int* __restrict__ adds, uint4* __restrict__ efrag) {
  const int gid  = blockIdx.x * E_THREADS + threadIdx.x;  // (b*32+ks)*64+lane
  const int lane = gid & 63;
  const int ksg  = gid >> 6;
  const int ks   = ksg & 31;
  const int b    = ksg >> 5;
  const int kg   = lane >> 4, l15 = lane & 15;
  const int j    = ks * 32 + kg * 8;

  const int* __restrict__ ap = adds + (size_t)b * SL + j;
  int av[8];
  #pragma unroll
  for (int e = 0; e < 8; ++e) av[e] = ap[e];

  #pragma unroll
  for (int qt = 0; qt < 4; ++qt) {
    const int q = qt * 16 + l15;
    unsigned w[4];
    #pragma unroll
    for (int u = 0; u < 4; ++u) {
      const unsigned lo = (av[2 * u]     == q) ? 0x3F80u : 0u;
      const unsigned hi = (av[2 * u + 1] == q) ? 0x3F80u : 0u;
      w[u] = lo | (hi << 16);
    }
    efrag[((size_t)(b * 32 + ks) * 4 + qt) * 64 + lane] = uint4{w[0], w[1], w[2], w[3]};
  }
}

// ---------------------------------------------------------------------------
// Kernel 1: T[row][q] = sum_j A[row][j]*(adds[j]==q) via MFMA, with A staged
// through LDS from CONTIGUOUS 64KB row-blocks (apply-style streaming — every
// scattered/partial-row variant pinned at 2.7-3.7 TB/s; contiguous gets 6+).
// MFMA math, hi/lo split, fragment semantics identical to R9 (verified).
// ---------------------------------------------------------------------------
__global__ __launch_bounds__(H_THREADS) void hist_mfma(
    const float* __restrict__ a, const uint4* __restrict__ efrag,
    float* __restrict__ tdump) {
  __shared__ float As[ROWS_PB][APAD];    // 66 KB, +8 pad: A-frag reads spread banks
  __shared__ float T_lds[ROWS_PB][66];   // 4.2 KB

  const int tid  = threadIdx.x;
  const int b    = blockIdx.x >> 6;      // 64 row-groups per batch
  const int rg   = blockIdx.x & 63;
  const int row0 = rg * ROWS_PB;

  // --- stage 16 full rows (64KB contiguous), NT, two 8-row passes ---
  {
    const f32x4* __restrict__ src =
        (const f32x4*)(a + ((size_t)b * SL + row0) * SL);
    f32x4 v[8];
    #pragma unroll
    for (int r = 0; r < 8; ++r)
      v[r] = __builtin_nontemporal_load(src + (size_t)r * (SL / 4) + tid);
    #pragma unroll
    for (int r = 0; r < 8; ++r) *(f32x4*)&As[r][4 * tid] = v[r];
    #pragma unroll
    for (int r = 0; r < 8; ++r)
      v[r] = __builtin_nontemporal_load(src + (size_t)(r + 8) * (SL / 4) + tid);
    #pragma unroll
    for (int r = 0; r < 8; ++r) *(f32x4*)&As[r + 8][4 * tid] = v[r];
  }
  __syncthreads();

  // --- K-loop: wave w owns q-tile w; A-frags from LDS; E-frags from global ---
  const int wid = tid >> 6, lane = tid & 63;
  const int kg = lane >> 4, l15 = lane & 15;
  const uint4* __restrict__ Eb =
      efrag + ((size_t)b * KSTEPS * 4 + wid) * 64 + lane;

  f32x4 acc = {0, 0, 0, 0};
  for (int ks0 = 0; ks0 < KSTEPS; ks0 += 4) {
    uint4 e4[4];
    #pragma unroll
    for (int j2 = 0; j2 < 4; ++j2)                 // 4 L2 loads in flight
      e4[j2] = Eb[(size_t)(ks0 + j2) * 256];
    #pragma unroll
    for (int j2 = 0; j2 < 4; ++j2) {
      const int ks = ks0 + j2;
      const f32x4 f0 = *(const f32x4*)&As[l15][ks * 32 + kg * 8];
      const f32x4 f1 = *(const f32x4*)&As[l15][ks * 32 + kg * 8 + 4];
      const float f[8] = {f0[0], f0[1], f0[2], f0[3], f1[0], f1[1], f1[2], f1[3]};
      bf16x8 ah, al;
      #pragma unroll
      for (int e = 0; e < 8; ++e) {                // R9-verified hi/lo split
        const unsigned u = __builtin_bit_cast(unsigned, f[e]);
        ah[e] = (short)(u >> 16);
        const float hf = __builtin_bit_cast(float, u & 0xFFFF0000u);
        const float lo = f[e] - hf;
        al[e] = (short)(__builtin_bit_cast(unsigned, lo) >> 16);
      }
      const bf16x8 bq = __builtin_bit_cast(bf16x8, e4[j2]);
      acc = __builtin_amdgcn_mfma_f32_16x16x32_bf16(ah, bq, acc, 0, 0, 0);
      acc = __builtin_amdgcn_mfma_f32_16x16x32_bf16(al, bq, acc, 0, 0, 0);
    }
  }

  // C/D layout (m89/R6-verified): col = lane&15, row = (lane>>4)*4 + reg
  #pragma unroll
  for (int r = 0; r < 4; ++r)
    T_lds[kg * 4 + r][wid * 16 + l15] = acc[r];
  __syncthreads();

  // --- dump T[16][64] coalesced to global scratch ---
  float* __restrict__ td = tdump + ((size_t)b * SL + row0) * 64;
  #pragma unroll
  for (int i = 0; i < 4; ++i) {
    const int idx = i * 256 + tid;
    td[idx] = T_lds[idx >> 6][idx & 63];
  }
}

// ---------------------------------------------------------------------------
// Kernel 2: per-batch bins. R10-verified counting sort of 1024 rows by p,
// then 8-deep pipelined register-run accumulation over tdump rows; LDS
// atomics only at run boundaries (~50 per thread-quarter).
// ---------------------------------------------------------------------------
__global__ __launch_bounds__(256) void reduce3(
    const float* __restrict__ tdump, const int* __restrict__ adds,
    float* __restrict__ g_part2) {
  __shared__ int   adds_s[SL];
  __shared__ int   orderR[SL];
  __shared__ int   cntR[NPOS], offm[NPOS];
  __shared__ float binL[NPOS * 64];    // 12.8 KB

  const int tid = threadIdx.x, b = blockIdx.x;
  ((int4*)adds_s)[tid] = ((const int4*)(adds + (size_t)b * SL))[tid];
  for (int k = tid; k < NPOS * 64; k += 256) binL[k] = 0.0f;
  if (tid < NPOS) cntR[tid] = 0;
  __syncthreads();
  for (int i = tid; i < SL; i += 256) atomicAdd(&cntR[adds_s[i]], 1);
  __syncthreads();
  if (tid == 0) {
    int run = 0;
    for (int c = 0; c < NPOS; ++c) { offm[c] = run; run += cntR[c]; }
  }
  __syncthreads();
  for (int i = tid; i < SL; i += 256)
    orderR[atomicAdd(&offm[adds_s[i]], 1)] = i;
  __syncthreads();

  const int q = tid & 63, qr = tid >> 6;        // wave-uniform quarter
  const float* __restrict__ td = tdump + (size_t)b * SL * 64;
  float s = 0.0f;
  int pcur = -1;
  for (int k0 = qr * 256; k0 < qr * 256 + 256; k0 += 8) {
    int rr[8]; float tv[8];
    #pragma unroll
    for (int u = 0; u < 8; ++u) rr[u] = orderR[k0 + u];
    #pragma unroll
    for (int u = 0; u < 8; ++u) tv[u] = td[(size_t)rr[u] * 64 + q];
    #pragma unroll
    for (int u = 0; u < 8; ++u) {
      const int p = adds_s[rr[u]];              // wave-uniform
      if (p != pcur) {
        if (pcur >= 0) atomicAdd(&binL[pcur * 64 + q], s);
        pcur = p; s = 0.0f;
      }
      s += tv[u];
    }
  }
  if (pcur >= 0) atomicAdd(&binL[pcur * 64 + q], s);
  __syncthreads();

  float* __restrict__ gp = g_part2 + (size_t)b * 3200;
  for (int k = tid; k < NPOS * 64; k += 256) gp[k] = binL[k];
}

// ---------------------------------------------------------------------------
// Kernel 3: g_hist[bin] = sum over 64 batches. Plain stores, no atomics.
// ---------------------------------------------------------------------------
__global__ __launch_bounds__(256) void reduce4(
    const float* __restrict__ g_part2, float* __restrict__ g_hist) {
  const int bin = blockIdx.x * 256 + threadIdx.x;
  if (bin >= NBINS) return;
  const int p = bin / NPOS, q = bin % NPOS;
  float s = 0.0f;
  #pragma unroll 8
  for (int bb = 0; bb < BZ; ++bb)
    s += g_part2[(size_t)bb * 3200 + p * 64 + q];
  g_hist[bin] = s;
}

// ---------------------------------------------------------------------------
// Kernel 4: out = s_arc + ALPHA * sigmoid(g_hist)[pos-pair bin].
// R16-verified: NT load + NT store, ~6.6 TB/s combined — unchanged.
// ---------------------------------------------------------------------------
__global__ __launch_bounds__(A_THREADS) void apply_kernel(
    const float* __restrict__ s, const int* __restrict__ pos,
    const float* __restrict__ g_hist, float* __restrict__ out) {
  __shared__ float sig[NBINS];
  __shared__ int   pos_s[SL];

  const int tid = threadIdx.x;
  const int b   = blockIdx.x / BLOCKS_PER_B;
  const int i0  = (blockIdx.x % BLOCKS_PER_B) * ROWS_PER_BLOCK;

  ((int4*)pos_s)[tid] = ((const int4*)(pos + (size_t)b * SL))[tid];
  for (int k = tid; k < NBINS; k += A_THREADS) {
    const float h = g_hist[k];
    sig[k] = 1.0f / (1.0f + __expf(-h));
  }
  __syncthreads();

  const int4 pj = ((const int4*)pos_s)[tid];
  const size_t rowoff = ((size_t)b * SL + i0) * SL;
  const f32x4* __restrict__ srow = (const f32x4*)(s + rowoff);
  f32x4* __restrict__ orow = (f32x4*)(out + rowoff);

  for (int r = 0; r < ROWS_PER_BLOCK; ++r) {
    const int base = pos_s[i0 + r] * NPOS;    // wave-uniform broadcast
    const f32x4 sv =
        __builtin_nontemporal_load(srow + (size_t)r * (SL / 4) + tid);
    f32x4 ov;
    ov[0] = sv[0] + ALPHA * sig[base + pj.x];
    ov[1] = sv[1] + ALPHA * sig[base + pj.y];
    ov[2] = sv[2] + ALPHA * sig[base + pj.z];
    ov[3] = sv[3] + ALPHA * sig[base + pj.w];
    __builtin_nontemporal_store(ov, orow + (size_t)r * (SL / 4) + tid);
  }
}

extern "C" void kernel_launch(void* const* d_in, const int* in_sizes, int n_in,
                              void* d_out, int out_size, void* d_ws, size_t ws_size,
                              hipStream_t stream) {
  const float* a_arc = (const float*)d_in[0];
  const float* s_arc = (const float*)d_in[1];
  const int*   adds  = (const int*)d_in[2];
  const int*   pos   = (const int*)d_in[3];
  float* out     = (float*)d_out;
  float* g_hist  = (float*)d_ws;                      // 2500 f
  float* g_part2 = g_hist + 8192;                     // 64 x 3200 f = 820 KB
  float* tdump   = g_hist + 1048576;                  // 4 MB off, 16.8 MB
  uint4* efrag   = (uint4*)(g_hist + 8388608);        // 32 MB off, 8.4 MB

  // No memset needed: every output buffer is fully overwritten with plain
  // stores each call (no global atomics anywhere).
  efrag_kernel<<<E_BLOCKS, E_THREADS, 0, stream>>>(adds, efrag);
  hist_mfma   <<<H_BLOCKS, H_THREADS, 0, stream>>>(a_arc, efrag, tdump);
  reduce3     <<<BZ, 256, 0, stream>>>(tdump, adds, g_part2);
  reduce4     <<<10, 256, 0, stream>>>(g_part2, g_hist);
  apply_kernel<<<A_BLOCKS, A_THREADS, 0, stream>>>(s_arc, pos, g_hist, out);
}